// Round 15
// baseline (760.282 us; speedup 1.0000x reference)
//
#include <hip/hip_runtime.h>
#include <hip/hip_bf16.h>

#define NN 100000
#define NE 300000
#define NG 2000
#define DD 256
#define NL 5
#define BN_EPS 1e-5f

typedef __bf16 bf16x8 __attribute__((ext_vector_type(8)));
typedef float floatx16 __attribute__((ext_vector_type(16)));

__device__ inline unsigned short f2bf(float x) {
  unsigned int u = __builtin_bit_cast(unsigned int, x);
  unsigned int r = u + 0x7FFFu + ((u >> 16) & 1u);
  return (unsigned short)(r >> 16);
}
__device__ inline float bf2f(unsigned short u) {
  return __builtin_bit_cast(float, (unsigned int)u << 16);
}
__device__ inline float4 bfu4(ushort4 u) {
  return make_float4(bf2f(u.x), bf2f(u.y), bf2f(u.z), bf2f(u.w));
}
__device__ inline float blo(unsigned int v) {
  return __builtin_bit_cast(float, v << 16);
}
__device__ inline float bhi(unsigned int v) {
  return __builtin_bit_cast(float, v & 0xFFFF0000u);
}
__device__ inline unsigned int pack2(float a, float b) {
  return (unsigned int)f2bf(a) | ((unsigned int)f2bf(b) << 16);
}

// ---------------- utility ----------------
__global__ __launch_bounds__(256) void k_zeroi(int* __restrict__ p, int n) {
  int i = blockIdx.x * 256 + threadIdx.x;
  if (i < n) p[i] = 0;
}

// ---------------- weight pack: all 18 matrices (gin1 x5, gin2 x5, vn1 x4, vn2 x4)
__global__ __launch_bounds__(256) void k_pack_all(
    const float* __restrict__ gw1, const float* __restrict__ gw2,
    const float* __restrict__ vw1, const float* __restrict__ vw2,
    unsigned short* __restrict__ Wf) {
  int idx = blockIdx.x * 256 + threadIdx.x;
  if (idx >= 18 * 65536) return;
  int m = idx >> 16, r = idx & 65535;
  int j = r & 7, lane = (r >> 3) & 63, ks = (r >> 9) & 15, nt = r >> 13;
  int n = nt * 32 + (lane & 31);
  int k = ks * 16 + ((lane >> 5) << 3) + j;
  const float* W;
  int mm;
  if (m < 5) { W = gw1; mm = m; }
  else if (m < 10) { W = gw2; mm = m - 5; }
  else if (m < 14) { W = vw1; mm = m - 10; }
  else { W = vw2; mm = m - 14; }
  Wf[idx] = f2bf(W[(size_t)mm * 65536 + k * 256 + n]);
}

// ---------------- CSR build ----------------
__global__ __launch_bounds__(256) void k_hist(const int* __restrict__ dst,
                                              int* __restrict__ cnt) {
  int e = blockIdx.x * 256 + threadIdx.x;
  if (e < NE) atomicAdd(&cnt[dst[e]], 1);
}

__global__ __launch_bounds__(1024) void k_bsum(const int* __restrict__ cnt,
                                               int* __restrict__ bsum) {
  __shared__ int sh[1024];
  int t = threadIdx.x, idx = blockIdx.x * 1024 + t;
  sh[t] = (idx < NN) ? cnt[idx] : 0;
  __syncthreads();
  for (int off = 512; off > 0; off >>= 1) {
    if (t < off) sh[t] += sh[t + off];
    __syncthreads();
  }
  if (t == 0) bsum[blockIdx.x] = sh[0];
}

__global__ __launch_bounds__(128) void k_scanb(const int* __restrict__ bsum,
                                               int* __restrict__ bbase, int nb) {
  __shared__ int sh[128];
  int t = threadIdx.x;
  sh[t] = (t < nb) ? bsum[t] : 0;
  __syncthreads();
  if (t == 0) {
    int run = 0;
    for (int i = 0; i < nb; ++i) { int v = sh[i]; sh[i] = run; run += v; }
  }
  __syncthreads();
  if (t < nb) bbase[t] = sh[t];
}

__global__ __launch_bounds__(1024) void k_rowptr(const int* __restrict__ cnt,
                                                 const int* __restrict__ bbase,
                                                 int* __restrict__ rowptr,
                                                 int* __restrict__ cursor) {
  __shared__ int sh[1024];
  int t = threadIdx.x, idx = blockIdx.x * 1024 + t;
  int v = (idx < NN) ? cnt[idx] : 0;
  sh[t] = v;
  __syncthreads();
  for (int off = 1; off < 1024; off <<= 1) {
    int add = (t >= off) ? sh[t - off] : 0;
    __syncthreads();
    sh[t] += add;
    __syncthreads();
  }
  if (idx < NN) {
    int excl = sh[t] - v + bbase[blockIdx.x];
    rowptr[idx] = excl;
    cursor[idx] = excl;
  }
  if (blockIdx.x == 0 && t == 0) rowptr[NN] = NE;
}

__global__ __launch_bounds__(256) void k_fill_src(const int* __restrict__ src,
                                                  const int* __restrict__ dst,
                                                  int* __restrict__ cursor,
                                                  int* __restrict__ ssrc) {
  int e = blockIdx.x * 256 + threadIdx.x;
  if (e >= NE) return;
  int pos = atomicAdd(&cursor[dst[e]], 1);
  ssrc[pos] = src[e];
}

// ---------------- graph bounds from sorted batch (no atomics) ----------------
__global__ __launch_bounds__(256) void k_gbounds(const int* __restrict__ batch,
                                                 int* __restrict__ gstart,
                                                 int* __restrict__ gend) {
  int n = blockIdx.x * 256 + threadIdx.x;
  if (n >= NN) return;
  int b = batch[n];
  if (n == 0 || batch[n - 1] != b) gstart[b] = n;
  if (n == NN - 1 || batch[n + 1] != b) gend[b] = n + 1;
}

// ---------------- node encode -> bf16 (16 nodes/block, w in LDS) ----------------
__global__ __launch_bounds__(256) void k_node_encode(
    const float* __restrict__ x, const float* __restrict__ w,
    const float* __restrict__ b, unsigned short* __restrict__ h16) {
  __shared__ float ws[20][256];
  __shared__ float xr[16][20];
  int tid = threadIdx.x;
  int n0 = blockIdx.x * 16;
  for (int p = tid; p < 20 * 64; p += 256) {
    int k = p >> 6, c4 = (p & 63) << 2;
    *(float4*)&ws[k][c4] = *(const float4*)(w + k * 256 + c4);
  }
  for (int p = tid; p < 320; p += 256) {
    int nn = p / 20, k = p - nn * 20;
    xr[nn][k] = x[(size_t)(n0 + nn) * 20 + k];
  }
  __syncthreads();
  int ln = tid >> 6, c4 = (tid & 63) << 2;
  float4 bv = *(const float4*)(b + c4);
  float a[4][4];
#pragma unroll
  for (int nn = 0; nn < 4; ++nn) {
    a[nn][0] = bv.x; a[nn][1] = bv.y; a[nn][2] = bv.z; a[nn][3] = bv.w;
  }
#pragma unroll
  for (int k = 0; k < 20; ++k) {
    float4 wv = *(float4*)&ws[k][c4];
#pragma unroll
    for (int nn = 0; nn < 4; ++nn) {
      float xv = xr[ln * 4 + nn][k];
      a[nn][0] = fmaf(xv, wv.x, a[nn][0]);
      a[nn][1] = fmaf(xv, wv.y, a[nn][1]);
      a[nn][2] = fmaf(xv, wv.z, a[nn][2]);
      a[nn][3] = fmaf(xv, wv.w, a[nn][3]);
    }
  }
#pragma unroll
  for (int nn = 0; nn < 4; ++nn) {
    int n = n0 + ln * 4 + nn;
    *(ushort4*)(h16 + (size_t)n * DD + c4) =
        make_ushort4(f2bf(a[nn][0]), f2bf(a[nn][1]), f2bf(a[nn][2]), f2bf(a[nn][3]));
  }
}

__global__ __launch_bounds__(256) void k_vn_init(const float* __restrict__ vnw,
                                                 unsigned short* __restrict__ vnb) {
  int i = blockIdx.x * 256 + threadIdx.x;
  vnb[i] = f2bf(vnw[i & (DD - 1)]);
}

// ---------------- u = h + vn[batch]  (streaming, bf16 in/out) ----------------
__global__ __launch_bounds__(256) void k_addvn_u(
    const unsigned short* __restrict__ h16, const unsigned short* __restrict__ vnb,
    const int* __restrict__ batch, unsigned short* __restrict__ u16) {
  int idx = blockIdx.x * 256 + threadIdx.x;      // uint4 index
  int n = idx >> 5, c8 = (idx & 31) << 3;
  int g = batch[n];
  uint4 hv = ((const uint4*)h16)[idx];
  uint4 vv = *(const uint4*)(vnb + (size_t)g * DD + c8);
  uint4 o;
  o.x = pack2(blo(hv.x) + blo(vv.x), bhi(hv.x) + bhi(vv.x));
  o.y = pack2(blo(hv.y) + blo(vv.y), bhi(hv.y) + bhi(vv.y));
  o.z = pack2(blo(hv.z) + blo(vv.z), bhi(hv.z) + bhi(vv.z));
  o.w = pack2(blo(hv.w) + blo(vv.w), bhi(hv.w) + bhi(vv.w));
  ((uint4*)u16)[idx] = o;
}

// ---------------- segment pool: one block per graph, no atomics ----------------
template <int MODE>
__global__ __launch_bounds__(256) void k_pool_seg(
    const unsigned short* __restrict__ h16, const unsigned short* __restrict__ vnb,
    const int* __restrict__ gstart, const int* __restrict__ gend,
    unsigned short* __restrict__ outb, float* __restrict__ outf) {
  __shared__ float4 sh[4][64];
  int g = blockIdx.x;
  int lane = threadIdx.x & 63, grp = threadIdx.x >> 6;
  int c4 = lane << 2;
  int s = gstart[g], e = gend[g];
  float4 acc = make_float4(0.f, 0.f, 0.f, 0.f);
  for (int n = s + grp; n < e; n += 4) {
    float4 v = bfu4(*(const ushort4*)(h16 + (size_t)n * DD + c4));
    acc.x += v.x; acc.y += v.y; acc.z += v.z; acc.w += v.w;
  }
  sh[grp][lane] = acc;
  __syncthreads();
  if (grp == 0) {
    float4 a0 = sh[0][lane], a1 = sh[1][lane], a2 = sh[2][lane], a3 = sh[3][lane];
    acc.x = a0.x + a1.x + a2.x + a3.x;
    acc.y = a0.y + a1.y + a2.y + a3.y;
    acc.z = a0.z + a1.z + a2.z + a3.z;
    acc.w = a0.w + a1.w + a2.w + a3.w;
    if (MODE == 0) {
      float4 v = bfu4(*(const ushort4*)(vnb + (size_t)g * DD + c4));
      acc.x += v.x; acc.y += v.y; acc.z += v.z; acc.w += v.w;
      *(ushort4*)(outb + (size_t)g * DD + c4) =
          make_ushort4(f2bf(acc.x), f2bf(acc.y), f2bf(acc.z), f2bf(acc.w));
    } else {
      *(float4*)(outf + (size_t)g * DD + c4) = acc;
    }
  }
}

// ---------------- fused GIN layer (512 threads): gather + MLP ----------------
// 32 rows/block, thread = (row, 16-col chunk): acc[16] fp32 (low VGPR -> 8
// waves/SIMD for the latency-bound scattered loads). 8 waves in MFMA phases,
// wave w owns cols [w*32,(w+1)*32).
__global__ __launch_bounds__(512) void k_gin_layer(
    const unsigned short* __restrict__ u16, const int* __restrict__ rowptr,
    const int* __restrict__ ssrc,
    const unsigned short* __restrict__ Wf1, const float* __restrict__ b1,
    const unsigned short* __restrict__ Wf2, const float* __restrict__ b2,
    const float* __restrict__ bng, const float* __restrict__ bnb,
    const float* __restrict__ bnm, const float* __restrict__ bnv,
    unsigned short* __restrict__ h16out) {
  __shared__ unsigned short As[16][2][32][8];  // 16 KB z fragments
  __shared__ unsigned short Bs[16][2][32][8];  // 16 KB hid fragments
  int tid = threadIdx.x;
  int m0 = blockIdx.x * 32;      // 3125 * 32 = 100000 exactly
  int r = tid & 31, q = tid >> 5;  // q in [0,16)
  int m = m0 + r;
  int cb = q << 4;               // col base (16 cols per thread)
  {
    float acc[16];
    const unsigned short* up = u16 + (size_t)m * DD + cb;
#pragma unroll
    for (int i = 0; i < 2; ++i) {
      uint4 v = *(const uint4*)(up + i * 8);
      acc[i * 8 + 0] = blo(v.x); acc[i * 8 + 1] = bhi(v.x);
      acc[i * 8 + 2] = blo(v.y); acc[i * 8 + 3] = bhi(v.y);
      acc[i * 8 + 4] = blo(v.z); acc[i * 8 + 5] = bhi(v.z);
      acc[i * 8 + 6] = blo(v.w); acc[i * 8 + 7] = bhi(v.w);
    }
    int b = rowptr[m], e = rowptr[m + 1];
    for (int t = b; t < e; ++t) {
      int s = ssrc[t];
      const unsigned short* sp = u16 + (size_t)s * DD + cb;
#pragma unroll
      for (int i = 0; i < 2; ++i) {
        uint4 v = *(const uint4*)(sp + i * 8);
        acc[i * 8 + 0] += blo(v.x); acc[i * 8 + 1] += bhi(v.x);
        acc[i * 8 + 2] += blo(v.y); acc[i * 8 + 3] += bhi(v.y);
        acc[i * 8 + 4] += blo(v.z); acc[i * 8 + 5] += bhi(v.z);
        acc[i * 8 + 6] += blo(v.w); acc[i * 8 + 7] += bhi(v.w);
      }
    }
    // cols cb+i*8+j -> fragment [ks=q][lh=i][row=r][j]
#pragma unroll
    for (int i = 0; i < 2; ++i) {
      uint4 o;
      o.x = pack2(acc[i * 8 + 0], acc[i * 8 + 1]);
      o.y = pack2(acc[i * 8 + 2], acc[i * 8 + 3]);
      o.z = pack2(acc[i * 8 + 4], acc[i * 8 + 5]);
      o.w = pack2(acc[i * 8 + 6], acc[i * 8 + 7]);
      *(uint4*)&As[q][i][r][0] = o;
    }
  }
  __syncthreads();

  int wave = tid >> 6, lane = tid & 63;  // wave in [0,8)
  int lrow = lane & 31, lhi = lane >> 5;

  // ---- phase 2: hid = relu(z @ W1 + b1) -> Bs ----
  {
    floatx16 facc = (floatx16)(0.f);
    const bf16x8* wf = (const bf16x8*)Wf1;
#pragma unroll
    for (int ks = 0; ks < 16; ++ks) {
      bf16x8 a = *(const bf16x8*)&As[ks][lhi][lrow][0];
      bf16x8 bb = wf[((wave * 16 + ks) << 6) + lane];
      facc = __builtin_amdgcn_mfma_f32_32x32x16_bf16(a, bb, facc, 0, 0, 0);
    }
    int c = wave * 32 + lrow;
    int ks2 = c >> 4, lh2 = (c >> 3) & 1, j2 = c & 7;
    float shf = b1[c];
#pragma unroll
    for (int reg = 0; reg < 16; ++reg) {
      int row = (reg & 3) + ((reg >> 2) << 3) + (lhi << 2);
      Bs[ks2][lh2][row][j2] = f2bf(fmaxf(facc[reg] + shf, 0.f));
    }
  }
  __syncthreads();

  // ---- phase 3: h = leaky0.1(bn(hid @ W2 + b2)) -> global ----
  {
    floatx16 facc = (floatx16)(0.f);
    const bf16x8* wf = (const bf16x8*)Wf2;
#pragma unroll
    for (int ks = 0; ks < 16; ++ks) {
      bf16x8 a = *(const bf16x8*)&Bs[ks][lhi][lrow][0];
      bf16x8 bb = wf[((wave * 16 + ks) << 6) + lane];
      facc = __builtin_amdgcn_mfma_f32_32x32x16_bf16(a, bb, facc, 0, 0, 0);
    }
    int c = wave * 32 + lrow;
    float s = bng[c] * rsqrtf(bnv[c] + BN_EPS);
    float shf = b2[c] * s + bnb[c] - bnm[c] * s;
#pragma unroll
    for (int reg = 0; reg < 16; ++reg) {
      int row = (reg & 3) + ((reg >> 2) << 3) + (lhi << 2);
      float v = facc[reg] * s + shf;
      v = (v > 0.f) ? v : 0.1f * v;
      h16out[(size_t)(m0 + row) * DD + c] = f2bf(v);
    }
  }
}

// ---------------- fused vn MLP: vnb = relu(bn2(relu(bn1(t0@W1+b1))@W2+b2)) -------
__global__ __launch_bounds__(256) void k_vn_mlp(
    const unsigned short* __restrict__ t0b,
    const unsigned short* __restrict__ Wf1, const float* __restrict__ b1,
    const float* __restrict__ bn1g, const float* __restrict__ bn1b,
    const float* __restrict__ bn1m, const float* __restrict__ bn1v,
    const unsigned short* __restrict__ Wf2, const float* __restrict__ b2,
    const float* __restrict__ bn2g, const float* __restrict__ bn2b,
    const float* __restrict__ bn2m, const float* __restrict__ bn2v,
    unsigned short* __restrict__ vnb) {
  __shared__ unsigned short As[2][16][2][32][8];  // 32 KB
  __shared__ unsigned short Bs[2][16][2][32][8];  // 32 KB
  int tid = threadIdx.x;
  int m0 = blockIdx.x * 64;
#pragma unroll
  for (int i = 0; i < 8; ++i) {
    int qq = i * 256 + tid;
    int lr = qq & 31, lh = (qq >> 5) & 1, ks = (qq >> 6) & 15, wm = qq >> 10;
    int m = m0 + wm * 32 + lr;
    uint4 v = make_uint4(0u, 0u, 0u, 0u);
    if (m < NG) v = *(const uint4*)(t0b + (size_t)m * DD + ks * 16 + lh * 8);
    *(uint4*)&As[wm][ks][lh][lr][0] = v;
  }
  __syncthreads();

  int wave = tid >> 6, lane = tid & 63;
  int wm = wave & 1, nhalf = wave >> 1;
  int lrow = lane & 31, lhi = lane >> 5;

  {
    floatx16 acc[4];
#pragma unroll
    for (int j = 0; j < 4; ++j) acc[j] = (floatx16)(0.f);
    const bf16x8* wf = (const bf16x8*)Wf1;
#pragma unroll
    for (int ks = 0; ks < 16; ++ks) {
      bf16x8 a = *(const bf16x8*)&As[wm][ks][lhi][lrow][0];
#pragma unroll
      for (int j = 0; j < 4; ++j) {
        int nt = nhalf * 4 + j;
        bf16x8 b = wf[((nt * 16 + ks) << 6) + lane];
        acc[j] = __builtin_amdgcn_mfma_f32_32x32x16_bf16(a, b, acc[j], 0, 0, 0);
      }
    }
#pragma unroll
    for (int j = 0; j < 4; ++j) {
      int c = nhalf * 128 + j * 32 + lrow;
      float s = bn1g[c] * rsqrtf(bn1v[c] + BN_EPS);
      float shf = b1[c] * s + bn1b[c] - bn1m[c] * s;
      int ks2 = c >> 4, lh2 = (c >> 3) & 1, j2 = c & 7;
#pragma unroll
      for (int reg = 0; reg < 16; ++reg) {
        int row = (reg & 3) + ((reg >> 2) << 3) + (lhi << 2);
        float v = fmaxf(acc[j][reg] * s + shf, 0.f);
        Bs[wm][ks2][lh2][row][j2] = f2bf(v);
      }
    }
  }
  __syncthreads();

  {
    floatx16 acc[4];
#pragma unroll
    for (int j = 0; j < 4; ++j) acc[j] = (floatx16)(0.f);
    const bf16x8* wf = (const bf16x8*)Wf2;
#pragma unroll
    for (int ks = 0; ks < 16; ++ks) {
      bf16x8 a = *(const bf16x8*)&Bs[wm][ks][lhi][lrow][0];
#pragma unroll
      for (int j = 0; j < 4; ++j) {
        int nt = nhalf * 4 + j;
        bf16x8 b = wf[((nt * 16 + ks) << 6) + lane];
        acc[j] = __builtin_amdgcn_mfma_f32_32x32x16_bf16(a, b, acc[j], 0, 0, 0);
      }
    }
#pragma unroll
    for (int j = 0; j < 4; ++j) {
      int c = nhalf * 128 + j * 32 + lrow;
      float s = bn2g[c] * rsqrtf(bn2v[c] + BN_EPS);
      float shf = b2[c] * s + bn2b[c] - bn2m[c] * s;
#pragma unroll
      for (int reg = 0; reg < 16; ++reg) {
        int row = (reg & 3) + ((reg >> 2) << 3) + (lhi << 2);
        int m = m0 + wm * 32 + row;
        if (m < NG) {
          float v = fmaxf(acc[j][reg] * s + shf, 0.f);
          vnb[(size_t)m * DD + c] = f2bf(v);
        }
      }
    }
  }
}

// ---------------- fused head: out = relu(relu(g@W1+b1)@W2+b2)@W3+b3, all fp32 -------
__global__ __launch_bounds__(256) void k_head(
    const float* __restrict__ X,
    const float* __restrict__ w1, const float* __restrict__ b1,
    const float* __restrict__ w2, const float* __restrict__ b2,
    const float* __restrict__ w3, const float* __restrict__ b3,
    float* __restrict__ out) {
  __shared__ float Xs[32][260];
  __shared__ float Ws[8192];
  __shared__ float H1[32][132];
  __shared__ float H2[32][68];
  __shared__ float W3s[64][12];
  int tid = threadIdx.x;
  int m0 = blockIdx.x * 32;
#pragma unroll
  for (int i = 0; i < 8; ++i) {
    int p = i * 256 + tid;
    int r = p >> 6, c4 = (p & 63) << 2;
    float4 v = make_float4(0.f, 0.f, 0.f, 0.f);
    if (m0 + r < NG) v = *(const float4*)(X + (size_t)(m0 + r) * 256 + c4);
    *(float4*)&Xs[r][c4] = v;
  }
  for (int p = tid; p < 704; p += 256) W3s[p / 11][p % 11] = w3[p];

  int r0 = (tid >> 5) << 2;
  int c0 = (tid & 31) << 2;
  float a1[4][4] = {};
  for (int k0 = 0; k0 < 256; k0 += 64) {
    __syncthreads();
#pragma unroll
    for (int i = 0; i < 8; ++i) {
      int p = i * 256 + tid;
      int r = p >> 5, c4 = (p & 31) << 2;
      *(float4*)&Ws[r * 128 + c4] = *(const float4*)(w1 + (size_t)(k0 + r) * 128 + c4);
    }
    __syncthreads();
#pragma unroll 4
    for (int k = 0; k < 64; ++k) {
      float4 wv = *(float4*)&Ws[k * 128 + c0];
      float xv[4];
#pragma unroll
      for (int i = 0; i < 4; ++i) xv[i] = Xs[r0 + i][k0 + k];
#pragma unroll
      for (int i = 0; i < 4; ++i) {
        a1[i][0] = fmaf(xv[i], wv.x, a1[i][0]);
        a1[i][1] = fmaf(xv[i], wv.y, a1[i][1]);
        a1[i][2] = fmaf(xv[i], wv.z, a1[i][2]);
        a1[i][3] = fmaf(xv[i], wv.w, a1[i][3]);
      }
    }
  }
#pragma unroll
  for (int i = 0; i < 4; ++i) {
    float4 o;
    o.x = fmaxf(a1[i][0] + b1[c0 + 0], 0.f);
    o.y = fmaxf(a1[i][1] + b1[c0 + 1], 0.f);
    o.z = fmaxf(a1[i][2] + b1[c0 + 2], 0.f);
    o.w = fmaxf(a1[i][3] + b1[c0 + 3], 0.f);
    *(float4*)&H1[r0 + i][c0] = o;
  }
  __syncthreads();
#pragma unroll
  for (int i = 0; i < 8; ++i) {
    int p = i * 256 + tid;
    int r = p >> 4, c4 = (p & 15) << 2;
    *(float4*)&Ws[r * 64 + c4] = *(const float4*)(w2 + (size_t)r * 64 + c4);
  }
  __syncthreads();
  int r2 = (tid >> 4) << 1;
  int c2 = (tid & 15) << 2;
  float a2[2][4] = {};
#pragma unroll 4
  for (int k = 0; k < 128; ++k) {
    float4 wv = *(float4*)&Ws[k * 64 + c2];
    float x0 = H1[r2][k], x1 = H1[r2 + 1][k];
    a2[0][0] = fmaf(x0, wv.x, a2[0][0]);
    a2[0][1] = fmaf(x0, wv.y, a2[0][1]);
    a2[0][2] = fmaf(x0, wv.z, a2[0][2]);
    a2[0][3] = fmaf(x0, wv.w, a2[0][3]);
    a2[1][0] = fmaf(x1, wv.x, a2[1][0]);
    a2[1][1] = fmaf(x1, wv.y, a2[1][1]);
    a2[1][2] = fmaf(x1, wv.z, a2[1][2]);
    a2[1][3] = fmaf(x1, wv.w, a2[1][3]);
  }
#pragma unroll
  for (int i = 0; i < 2; ++i) {
    float4 o;
    o.x = fmaxf(a2[i][0] + b2[c2 + 0], 0.f);
    o.y = fmaxf(a2[i][1] + b2[c2 + 1], 0.f);
    o.z = fmaxf(a2[i][2] + b2[c2 + 2], 0.f);
    o.w = fmaxf(a2[i][3] + b2[c2 + 3], 0.f);
    *(float4*)&H2[r2 + i][c2] = o;
  }
  __syncthreads();
  for (int p = tid; p < 352; p += 256) {
    int r = p / 11, c = p - (p / 11) * 11;
    float acc = b3[c];
#pragma unroll 8
    for (int k = 0; k < 64; ++k) acc = fmaf(H2[r][k], W3s[k][c], acc);
    if (m0 + r < NG) out[(size_t)(m0 + r) * 11 + c] = acc;
  }
}

extern "C" void kernel_launch(void* const* d_in, const int* in_sizes, int n_in,
                              void* d_out, int out_size, void* d_ws, size_t ws_size,
                              hipStream_t stream) {
  const float* x      = (const float*)d_in[0];
  const int*   ei     = (const int*)d_in[1];
  const int*   batch  = (const int*)d_in[2];
  const float* node_w = (const float*)d_in[3];
  const float* node_b = (const float*)d_in[4];
  const float* vn_w   = (const float*)d_in[5];
  const float* gin_w1 = (const float*)d_in[6];
  const float* gin_b1 = (const float*)d_in[7];
  const float* gin_w2 = (const float*)d_in[8];
  const float* gin_b2 = (const float*)d_in[9];
  const float* bn_g   = (const float*)d_in[10];
  const float* bn_b   = (const float*)d_in[11];
  const float* bn_m   = (const float*)d_in[12];
  const float* bn_v   = (const float*)d_in[13];
  const float* vn_w1  = (const float*)d_in[14];
  const float* vn_b1  = (const float*)d_in[15];
  const float* vbn1g  = (const float*)d_in[16];
  const float* vbn1b  = (const float*)d_in[17];
  const float* vbn1m  = (const float*)d_in[18];
  const float* vbn1v  = (const float*)d_in[19];
  const float* vn_w2  = (const float*)d_in[20];
  const float* vn_b2  = (const float*)d_in[21];
  const float* vbn2g  = (const float*)d_in[22];
  const float* vbn2b  = (const float*)d_in[23];
  const float* vbn2m  = (const float*)d_in[24];
  const float* vbn2v  = (const float*)d_in[25];
  const float* head_w1 = (const float*)d_in[26];
  const float* head_b1 = (const float*)d_in[27];
  const float* head_w2 = (const float*)d_in[28];
  const float* head_b2 = (const float*)d_in[29];
  const float* head_w3 = (const float*)d_in[30];
  const float* head_b3 = (const float*)d_in[31];

  // ---- workspace layout (~110 MB) ----
  unsigned short* h16   = (unsigned short*)d_ws;          // [NN*DD]
  unsigned short* u16   = h16 + (size_t)NN * DD;          // [NN*DD]
  unsigned short* vnb   = u16 + (size_t)NN * DD;          // [NG*DD]
  unsigned short* t0b   = vnb + (size_t)NG * DD;          // [NG*DD]
  unsigned short* wf1   = t0b + (size_t)NG * DD;          // [5*65536]
  unsigned short* wf2   = wf1 + 5 * 65536;                // [5*65536]
  unsigned short* wfv1  = wf2 + 5 * 65536;                // [4*65536]
  unsigned short* wfv2  = wfv1 + 4 * 65536;               // [4*65536]
  float* t0f  = (float*)(wfv2 + 4 * 65536);               // [NG*DD]
  int* rowptr = (int*)(t0f + (size_t)NG * DD);            // [NN+1]
  int* cursor = rowptr + NN + 1;                          // [NN]     (zeroed together
  int* gstart = cursor + NN;                              // [NG]      with gstart/gend)
  int* gend   = gstart + NG;                              // [NG]
  int* ssrc   = gend + NG;                                // [NE]
  int* bsum   = ssrc + NE;                                // [128]
  int* bbase  = bsum + 128;                               // [128]

  const int* src = ei;
  const int* dst = ei + NE;

  const int NB = (NN + 1023) / 1024;  // 98

  // ---- once per launch: weight pack + CSR + graph bounds ----
  k_pack_all<<<(18 * 65536 + 255) / 256, 256, 0, stream>>>(
      gin_w1, gin_w2, vn_w1, vn_w2, wf1);
  k_zeroi<<<(NN + 2 * NG + 255) / 256, 256, 0, stream>>>(cursor, NN + 2 * NG);
  k_hist<<<(NE + 255) / 256, 256, 0, stream>>>(dst, cursor);
  k_bsum<<<NB, 1024, 0, stream>>>(cursor, bsum);
  k_scanb<<<1, 128, 0, stream>>>(bsum, bbase, NB);
  k_rowptr<<<NB, 1024, 0, stream>>>(cursor, bbase, rowptr, cursor);
  k_fill_src<<<(NE + 255) / 256, 256, 0, stream>>>(src, dst, cursor, ssrc);
  k_gbounds<<<(NN + 255) / 256, 256, 0, stream>>>(batch, gstart, gend);

  k_node_encode<<<NN / 16, 256, 0, stream>>>(x, node_w, node_b, h16);
  k_vn_init<<<NG * DD / 256, 256, 0, stream>>>(vn_w, vnb);

  const int GG_NN = NN / 32;          // 3125
  const int GM_NG = (NG + 63) / 64;   // 32
  const int NU4   = NN * DD / 8;      // uint4 count

  for (int l = 0; l < NL; ++l) {
    // u = h + vn[batch]
    k_addvn_u<<<NU4 / 256, 256, 0, stream>>>(h16, vnb, batch, u16);
    // h = leaky(bn(relu((u[m]+sum u[src]) @ W1 + b1) @ W2 + b2))  [one kernel]
    k_gin_layer<<<GG_NN, 512, 0, stream>>>(
        u16, rowptr, ssrc,
        wf1 + (size_t)l * 65536, gin_b1 + l * DD,
        wf2 + (size_t)l * 65536, gin_b2 + l * DD,
        bn_g + l * DD, bn_b + l * DD, bn_m + l * DD, bn_v + l * DD, h16);
    if (l < NL - 1) {
      // t0 = pool(h) + vn  (bf16), then vn = vn_mlp(t0)  [one kernel]
      k_pool_seg<0><<<NG, 256, 0, stream>>>(h16, vnb, gstart, gend, t0b, nullptr);
      k_vn_mlp<<<GM_NG, 256, 0, stream>>>(
          t0b,
          wfv1 + (size_t)l * 65536, vn_b1 + l * DD,
          vbn1g + l * DD, vbn1b + l * DD, vbn1m + l * DD, vbn1v + l * DD,
          wfv2 + (size_t)l * 65536, vn_b2 + l * DD,
          vbn2g + l * DD, vbn2b + l * DD, vbn2m + l * DD, vbn2v + l * DD,
          vnb);
    }
  }
  // final pool (fp32, no vn) + fused head
  k_pool_seg<1><<<NG, 256, 0, stream>>>(h16, nullptr, gstart, gend, nullptr, t0f);
  k_head<<<(NG + 31) / 32, 256, 0, stream>>>(
      t0f, head_w1, head_b1, head_w2, head_b2, head_w3, head_b3, (float*)d_out);
}

// Round 16
// 717.731 us; speedup vs baseline: 1.0593x; 1.0593x over previous
//
#include <hip/hip_runtime.h>
#include <hip/hip_bf16.h>

#define NN 100000
#define NE 300000
#define NG 2000
#define DD 256
#define NL 5
#define BN_EPS 1e-5f

typedef __bf16 bf16x8 __attribute__((ext_vector_type(8)));
typedef float floatx16 __attribute__((ext_vector_type(16)));

__device__ inline unsigned short f2bf(float x) {
  unsigned int u = __builtin_bit_cast(unsigned int, x);
  unsigned int r = u + 0x7FFFu + ((u >> 16) & 1u);
  return (unsigned short)(r >> 16);
}
__device__ inline float bf2f(unsigned short u) {
  return __builtin_bit_cast(float, (unsigned int)u << 16);
}
__device__ inline float4 bfu4(ushort4 u) {
  return make_float4(bf2f(u.x), bf2f(u.y), bf2f(u.z), bf2f(u.w));
}
__device__ inline float blo(unsigned int v) {
  return __builtin_bit_cast(float, v << 16);
}
__device__ inline float bhi(unsigned int v) {
  return __builtin_bit_cast(float, v & 0xFFFF0000u);
}
__device__ inline unsigned int pack2(float a, float b) {
  return (unsigned int)f2bf(a) | ((unsigned int)f2bf(b) << 16);
}

// ---------------- utility ----------------
__global__ __launch_bounds__(256) void k_zeroi(int* __restrict__ p, int n) {
  int i = blockIdx.x * 256 + threadIdx.x;
  if (i < n) p[i] = 0;
}

// ---------------- weight pack (18 matrices) + vn init, one dispatch ----------------
__global__ __launch_bounds__(256) void k_pack_all(
    const float* __restrict__ gw1, const float* __restrict__ gw2,
    const float* __restrict__ vw1, const float* __restrict__ vw2,
    unsigned short* __restrict__ Wf,
    const float* __restrict__ vnw, unsigned short* __restrict__ vnb) {
  int idx = blockIdx.x * 256 + threadIdx.x;
  if (idx >= 18 * 65536) {
    int i = idx - 18 * 65536;
    if (i < NG * DD) vnb[i] = f2bf(vnw[i & (DD - 1)]);
    return;
  }
  int m = idx >> 16, r = idx & 65535;
  int j = r & 7, lane = (r >> 3) & 63, ks = (r >> 9) & 15, nt = r >> 13;
  int n = nt * 32 + (lane & 31);
  int k = ks * 16 + ((lane >> 5) << 3) + j;
  const float* W;
  int mm;
  if (m < 5) { W = gw1; mm = m; }
  else if (m < 10) { W = gw2; mm = m - 5; }
  else if (m < 14) { W = vw1; mm = m - 10; }
  else { W = vw2; mm = m - 14; }
  Wf[idx] = f2bf(W[(size_t)mm * 65536 + k * 256 + n]);
}

// ---------------- CSR build ----------------
__global__ __launch_bounds__(256) void k_hist(const int* __restrict__ dst,
                                              int* __restrict__ cnt) {
  int e = blockIdx.x * 256 + threadIdx.x;
  if (e < NE) atomicAdd(&cnt[dst[e]], 1);
}

__global__ __launch_bounds__(1024) void k_bsum(const int* __restrict__ cnt,
                                               int* __restrict__ bsum) {
  __shared__ int sh[1024];
  int t = threadIdx.x, idx = blockIdx.x * 1024 + t;
  sh[t] = (idx < NN) ? cnt[idx] : 0;
  __syncthreads();
  for (int off = 512; off > 0; off >>= 1) {
    if (t < off) sh[t] += sh[t + off];
    __syncthreads();
  }
  if (t == 0) bsum[blockIdx.x] = sh[0];
}

__global__ __launch_bounds__(128) void k_scanb(const int* __restrict__ bsum,
                                               int* __restrict__ bbase, int nb) {
  __shared__ int sh[128];
  int t = threadIdx.x;
  sh[t] = (t < nb) ? bsum[t] : 0;
  __syncthreads();
  if (t == 0) {
    int run = 0;
    for (int i = 0; i < nb; ++i) { int v = sh[i]; sh[i] = run; run += v; }
  }
  __syncthreads();
  if (t < nb) bbase[t] = sh[t];
}

__global__ __launch_bounds__(1024) void k_rowptr(const int* __restrict__ cnt,
                                                 const int* __restrict__ bbase,
                                                 int* __restrict__ rowptr,
                                                 int* __restrict__ cursor) {
  __shared__ int sh[1024];
  int t = threadIdx.x, idx = blockIdx.x * 1024 + t;
  int v = (idx < NN) ? cnt[idx] : 0;
  sh[t] = v;
  __syncthreads();
  for (int off = 1; off < 1024; off <<= 1) {
    int add = (t >= off) ? sh[t - off] : 0;
    __syncthreads();
    sh[t] += add;
    __syncthreads();
  }
  if (idx < NN) {
    int excl = sh[t] - v + bbase[blockIdx.x];
    rowptr[idx] = excl;
    cursor[idx] = excl;
  }
  if (blockIdx.x == 0 && t == 0) rowptr[NN] = NE;
}

__global__ __launch_bounds__(256) void k_fill_src(const int* __restrict__ src,
                                                  const int* __restrict__ dst,
                                                  int* __restrict__ cursor,
                                                  int* __restrict__ ssrc) {
  int e = blockIdx.x * 256 + threadIdx.x;
  if (e >= NE) return;
  int pos = atomicAdd(&cursor[dst[e]], 1);
  ssrc[pos] = src[e];
}

// ---------------- graph bounds from sorted batch (no atomics) ----------------
__global__ __launch_bounds__(256) void k_gbounds(const int* __restrict__ batch,
                                                 int* __restrict__ gstart,
                                                 int* __restrict__ gend) {
  int n = blockIdx.x * 256 + threadIdx.x;
  if (n >= NN) return;
  int b = batch[n];
  if (n == 0 || batch[n - 1] != b) gstart[b] = n;
  if (n == NN - 1 || batch[n + 1] != b) gend[b] = n + 1;
}

// ---------------- node encode -> bf16 (16 nodes/block, w in LDS) ----------------
__global__ __launch_bounds__(256) void k_node_encode(
    const float* __restrict__ x, const float* __restrict__ w,
    const float* __restrict__ b, unsigned short* __restrict__ h16) {
  __shared__ float ws[20][256];
  __shared__ float xr[16][20];
  int tid = threadIdx.x;
  int n0 = blockIdx.x * 16;
  for (int p = tid; p < 20 * 64; p += 256) {
    int k = p >> 6, c4 = (p & 63) << 2;
    *(float4*)&ws[k][c4] = *(const float4*)(w + k * 256 + c4);
  }
  for (int p = tid; p < 320; p += 256) {
    int nn = p / 20, k = p - nn * 20;
    xr[nn][k] = x[(size_t)(n0 + nn) * 20 + k];
  }
  __syncthreads();
  int ln = tid >> 6, c4 = (tid & 63) << 2;
  float4 bv = *(const float4*)(b + c4);
  float a[4][4];
#pragma unroll
  for (int nn = 0; nn < 4; ++nn) {
    a[nn][0] = bv.x; a[nn][1] = bv.y; a[nn][2] = bv.z; a[nn][3] = bv.w;
  }
#pragma unroll
  for (int k = 0; k < 20; ++k) {
    float4 wv = *(float4*)&ws[k][c4];
#pragma unroll
    for (int nn = 0; nn < 4; ++nn) {
      float xv = xr[ln * 4 + nn][k];
      a[nn][0] = fmaf(xv, wv.x, a[nn][0]);
      a[nn][1] = fmaf(xv, wv.y, a[nn][1]);
      a[nn][2] = fmaf(xv, wv.z, a[nn][2]);
      a[nn][3] = fmaf(xv, wv.w, a[nn][3]);
    }
  }
#pragma unroll
  for (int nn = 0; nn < 4; ++nn) {
    int n = n0 + ln * 4 + nn;
    *(ushort4*)(h16 + (size_t)n * DD + c4) =
        make_ushort4(f2bf(a[nn][0]), f2bf(a[nn][1]), f2bf(a[nn][2]), f2bf(a[nn][3]));
  }
}

// ---------------- u = h + vn[batch]  (streaming, bf16 in/out) ----------------
__global__ __launch_bounds__(256) void k_addvn_u(
    const unsigned short* __restrict__ h16, const unsigned short* __restrict__ vnb,
    const int* __restrict__ batch, unsigned short* __restrict__ u16) {
  int idx = blockIdx.x * 256 + threadIdx.x;      // uint4 index
  int n = idx >> 5, c8 = (idx & 31) << 3;
  int g = batch[n];
  uint4 hv = ((const uint4*)h16)[idx];
  uint4 vv = *(const uint4*)(vnb + (size_t)g * DD + c8);
  uint4 o;
  o.x = pack2(blo(hv.x) + blo(vv.x), bhi(hv.x) + bhi(vv.x));
  o.y = pack2(blo(hv.y) + blo(vv.y), bhi(hv.y) + bhi(vv.y));
  o.z = pack2(blo(hv.z) + blo(vv.z), bhi(hv.z) + bhi(vv.z));
  o.w = pack2(blo(hv.w) + blo(vv.w), bhi(hv.w) + bhi(vv.w));
  ((uint4*)u16)[idx] = o;
}

// ---------------- segment pool: one block per graph, no atomics ----------------
template <int MODE>
__global__ __launch_bounds__(256) void k_pool_seg(
    const unsigned short* __restrict__ h16, const unsigned short* __restrict__ vnb,
    const int* __restrict__ gstart, const int* __restrict__ gend,
    unsigned short* __restrict__ outb, float* __restrict__ outf) {
  __shared__ float4 sh[4][64];
  int g = blockIdx.x;
  int lane = threadIdx.x & 63, grp = threadIdx.x >> 6;
  int c4 = lane << 2;
  int s = gstart[g], e = gend[g];
  float4 acc = make_float4(0.f, 0.f, 0.f, 0.f);
  for (int n = s + grp; n < e; n += 4) {
    float4 v = bfu4(*(const ushort4*)(h16 + (size_t)n * DD + c4));
    acc.x += v.x; acc.y += v.y; acc.z += v.z; acc.w += v.w;
  }
  sh[grp][lane] = acc;
  __syncthreads();
  if (grp == 0) {
    float4 a0 = sh[0][lane], a1 = sh[1][lane], a2 = sh[2][lane], a3 = sh[3][lane];
    acc.x = a0.x + a1.x + a2.x + a3.x;
    acc.y = a0.y + a1.y + a2.y + a3.y;
    acc.z = a0.z + a1.z + a2.z + a3.z;
    acc.w = a0.w + a1.w + a2.w + a3.w;
    if (MODE == 0) {
      float4 v = bfu4(*(const ushort4*)(vnb + (size_t)g * DD + c4));
      acc.x += v.x; acc.y += v.y; acc.z += v.z; acc.w += v.w;
      *(ushort4*)(outb + (size_t)g * DD + c4) =
          make_ushort4(f2bf(acc.x), f2bf(acc.y), f2bf(acc.z), f2bf(acc.w));
    } else {
      *(float4*)(outf + (size_t)g * DD + c4) = acc;
    }
  }
}

// ---------------- fused GIN layer (512 threads): gather + MLP ----------------
// 32 rows/block, thread = (row = tid>>4, 16-col chunk = tid&15): a wave spans
// only 4 rows -> edge-loop divergence is max over 4 (not 32) lists, and loads
// coalesce into 4 x 256 B contiguous runs. acc[16] fp32 (low VGPR). 8 waves in
// MFMA phases, wave w owns cols [w*32,(w+1)*32).
__global__ __launch_bounds__(512) void k_gin_layer(
    const unsigned short* __restrict__ u16, const int* __restrict__ rowptr,
    const int* __restrict__ ssrc,
    const unsigned short* __restrict__ Wf1, const float* __restrict__ b1,
    const unsigned short* __restrict__ Wf2, const float* __restrict__ b2,
    const float* __restrict__ bng, const float* __restrict__ bnb,
    const float* __restrict__ bnm, const float* __restrict__ bnv,
    unsigned short* __restrict__ h16out) {
  __shared__ unsigned short As[16][2][32][8];  // 16 KB z fragments
  __shared__ unsigned short Bs[16][2][32][8];  // 16 KB hid fragments
  int tid = threadIdx.x;
  int m0 = blockIdx.x * 32;      // 3125 * 32 = 100000 exactly
  int r = tid >> 4, q = tid & 15;  // row 0..31, col chunk 0..15
  int m = m0 + r;
  int cb = q << 4;               // col base (16 cols per thread)
  {
    float acc[16];
    const unsigned short* up = u16 + (size_t)m * DD + cb;
#pragma unroll
    for (int i = 0; i < 2; ++i) {
      uint4 v = *(const uint4*)(up + i * 8);
      acc[i * 8 + 0] = blo(v.x); acc[i * 8 + 1] = bhi(v.x);
      acc[i * 8 + 2] = blo(v.y); acc[i * 8 + 3] = bhi(v.y);
      acc[i * 8 + 4] = blo(v.z); acc[i * 8 + 5] = bhi(v.z);
      acc[i * 8 + 6] = blo(v.w); acc[i * 8 + 7] = bhi(v.w);
    }
    int b = rowptr[m], e = rowptr[m + 1];
    for (int t = b; t < e; ++t) {
      int s = ssrc[t];
      const unsigned short* sp = u16 + (size_t)s * DD + cb;
#pragma unroll
      for (int i = 0; i < 2; ++i) {
        uint4 v = *(const uint4*)(sp + i * 8);
        acc[i * 8 + 0] += blo(v.x); acc[i * 8 + 1] += bhi(v.x);
        acc[i * 8 + 2] += blo(v.y); acc[i * 8 + 3] += bhi(v.y);
        acc[i * 8 + 4] += blo(v.z); acc[i * 8 + 5] += bhi(v.z);
        acc[i * 8 + 6] += blo(v.w); acc[i * 8 + 7] += bhi(v.w);
      }
    }
    // cols cb+i*8+j -> fragment [ks=q][lh=i][row=r][j]
#pragma unroll
    for (int i = 0; i < 2; ++i) {
      uint4 o;
      o.x = pack2(acc[i * 8 + 0], acc[i * 8 + 1]);
      o.y = pack2(acc[i * 8 + 2], acc[i * 8 + 3]);
      o.z = pack2(acc[i * 8 + 4], acc[i * 8 + 5]);
      o.w = pack2(acc[i * 8 + 6], acc[i * 8 + 7]);
      *(uint4*)&As[q][i][r][0] = o;
    }
  }
  __syncthreads();

  int wave = tid >> 6, lane = tid & 63;  // wave in [0,8)
  int lrow = lane & 31, lhi = lane >> 5;

  // ---- phase 2: hid = relu(z @ W1 + b1) -> Bs ----
  {
    floatx16 facc = (floatx16)(0.f);
    const bf16x8* wf = (const bf16x8*)Wf1;
#pragma unroll
    for (int ks = 0; ks < 16; ++ks) {
      bf16x8 a = *(const bf16x8*)&As[ks][lhi][lrow][0];
      bf16x8 bb = wf[((wave * 16 + ks) << 6) + lane];
      facc = __builtin_amdgcn_mfma_f32_32x32x16_bf16(a, bb, facc, 0, 0, 0);
    }
    int c = wave * 32 + lrow;
    int ks2 = c >> 4, lh2 = (c >> 3) & 1, j2 = c & 7;
    float shf = b1[c];
#pragma unroll
    for (int reg = 0; reg < 16; ++reg) {
      int row = (reg & 3) + ((reg >> 2) << 3) + (lhi << 2);
      Bs[ks2][lh2][row][j2] = f2bf(fmaxf(facc[reg] + shf, 0.f));
    }
  }
  __syncthreads();

  // ---- phase 3: h = leaky0.1(bn(hid @ W2 + b2)) -> global ----
  {
    floatx16 facc = (floatx16)(0.f);
    const bf16x8* wf = (const bf16x8*)Wf2;
#pragma unroll
    for (int ks = 0; ks < 16; ++ks) {
      bf16x8 a = *(const bf16x8*)&Bs[ks][lhi][lrow][0];
      bf16x8 bb = wf[((wave * 16 + ks) << 6) + lane];
      facc = __builtin_amdgcn_mfma_f32_32x32x16_bf16(a, bb, facc, 0, 0, 0);
    }
    int c = wave * 32 + lrow;
    float s = bng[c] * rsqrtf(bnv[c] + BN_EPS);
    float shf = b2[c] * s + bnb[c] - bnm[c] * s;
#pragma unroll
    for (int reg = 0; reg < 16; ++reg) {
      int row = (reg & 3) + ((reg >> 2) << 3) + (lhi << 2);
      float v = facc[reg] * s + shf;
      v = (v > 0.f) ? v : 0.1f * v;
      h16out[(size_t)(m0 + row) * DD + c] = f2bf(v);
    }
  }
}

// ---------------- fused vn MLP: vnb = relu(bn2(relu(bn1(t0@W1+b1))@W2+b2)) -------
__global__ __launch_bounds__(256) void k_vn_mlp(
    const unsigned short* __restrict__ t0b,
    const unsigned short* __restrict__ Wf1, const float* __restrict__ b1,
    const float* __restrict__ bn1g, const float* __restrict__ bn1b,
    const float* __restrict__ bn1m, const float* __restrict__ bn1v,
    const unsigned short* __restrict__ Wf2, const float* __restrict__ b2,
    const float* __restrict__ bn2g, const float* __restrict__ bn2b,
    const float* __restrict__ bn2m, const float* __restrict__ bn2v,
    unsigned short* __restrict__ vnb) {
  __shared__ unsigned short As[2][16][2][32][8];  // 32 KB
  __shared__ unsigned short Bs[2][16][2][32][8];  // 32 KB
  int tid = threadIdx.x;
  int m0 = blockIdx.x * 64;
#pragma unroll
  for (int i = 0; i < 8; ++i) {
    int qq = i * 256 + tid;
    int lr = qq & 31, lh = (qq >> 5) & 1, ks = (qq >> 6) & 15, wm = qq >> 10;
    int m = m0 + wm * 32 + lr;
    uint4 v = make_uint4(0u, 0u, 0u, 0u);
    if (m < NG) v = *(const uint4*)(t0b + (size_t)m * DD + ks * 16 + lh * 8);
    *(uint4*)&As[wm][ks][lh][lr][0] = v;
  }
  __syncthreads();

  int wave = tid >> 6, lane = tid & 63;
  int wm = wave & 1, nhalf = wave >> 1;
  int lrow = lane & 31, lhi = lane >> 5;

  {
    floatx16 acc[4];
#pragma unroll
    for (int j = 0; j < 4; ++j) acc[j] = (floatx16)(0.f);
    const bf16x8* wf = (const bf16x8*)Wf1;
#pragma unroll
    for (int ks = 0; ks < 16; ++ks) {
      bf16x8 a = *(const bf16x8*)&As[wm][ks][lhi][lrow][0];
#pragma unroll
      for (int j = 0; j < 4; ++j) {
        int nt = nhalf * 4 + j;
        bf16x8 b = wf[((nt * 16 + ks) << 6) + lane];
        acc[j] = __builtin_amdgcn_mfma_f32_32x32x16_bf16(a, b, acc[j], 0, 0, 0);
      }
    }
#pragma unroll
    for (int j = 0; j < 4; ++j) {
      int c = nhalf * 128 + j * 32 + lrow;
      float s = bn1g[c] * rsqrtf(bn1v[c] + BN_EPS);
      float shf = b1[c] * s + bn1b[c] - bn1m[c] * s;
      int ks2 = c >> 4, lh2 = (c >> 3) & 1, j2 = c & 7;
#pragma unroll
      for (int reg = 0; reg < 16; ++reg) {
        int row = (reg & 3) + ((reg >> 2) << 3) + (lhi << 2);
        float v = fmaxf(acc[j][reg] * s + shf, 0.f);
        Bs[wm][ks2][lh2][row][j2] = f2bf(v);
      }
    }
  }
  __syncthreads();

  {
    floatx16 acc[4];
#pragma unroll
    for (int j = 0; j < 4; ++j) acc[j] = (floatx16)(0.f);
    const bf16x8* wf = (const bf16x8*)Wf2;
#pragma unroll
    for (int ks = 0; ks < 16; ++ks) {
      bf16x8 a = *(const bf16x8*)&Bs[wm][ks][lhi][lrow][0];
#pragma unroll
      for (int j = 0; j < 4; ++j) {
        int nt = nhalf * 4 + j;
        bf16x8 b = wf[((nt * 16 + ks) << 6) + lane];
        acc[j] = __builtin_amdgcn_mfma_f32_32x32x16_bf16(a, b, acc[j], 0, 0, 0);
      }
    }
#pragma unroll
    for (int j = 0; j < 4; ++j) {
      int c = nhalf * 128 + j * 32 + lrow;
      float s = bn2g[c] * rsqrtf(bn2v[c] + BN_EPS);
      float shf = b2[c] * s + bn2b[c] - bn2m[c] * s;
#pragma unroll
      for (int reg = 0; reg < 16; ++reg) {
        int row = (reg & 3) + ((reg >> 2) << 3) + (lhi << 2);
        int m = m0 + wm * 32 + row;
        if (m < NG) {
          float v = fmaxf(acc[j][reg] * s + shf, 0.f);
          vnb[(size_t)m * DD + c] = f2bf(v);
        }
      }
    }
  }
}

// ---------------- fused head: out = relu(relu(g@W1+b1)@W2+b2)@W3+b3, all fp32 -------
__global__ __launch_bounds__(256) void k_head(
    const float* __restrict__ X,
    const float* __restrict__ w1, const float* __restrict__ b1,
    const float* __restrict__ w2, const float* __restrict__ b2,
    const float* __restrict__ w3, const float* __restrict__ b3,
    float* __restrict__ out) {
  __shared__ float Xs[32][260];
  __shared__ float Ws[8192];
  __shared__ float H1[32][132];
  __shared__ float H2[32][68];
  __shared__ float W3s[64][12];
  int tid = threadIdx.x;
  int m0 = blockIdx.x * 32;
#pragma unroll
  for (int i = 0; i < 8; ++i) {
    int p = i * 256 + tid;
    int r = p >> 6, c4 = (p & 63) << 2;
    float4 v = make_float4(0.f, 0.f, 0.f, 0.f);
    if (m0 + r < NG) v = *(const float4*)(X + (size_t)(m0 + r) * 256 + c4);
    *(float4*)&Xs[r][c4] = v;
  }
  for (int p = tid; p < 704; p += 256) W3s[p / 11][p % 11] = w3[p];

  int r0 = (tid >> 5) << 2;
  int c0 = (tid & 31) << 2;
  float a1[4][4] = {};
  for (int k0 = 0; k0 < 256; k0 += 64) {
    __syncthreads();
#pragma unroll
    for (int i = 0; i < 8; ++i) {
      int p = i * 256 + tid;
      int r = p >> 5, c4 = (p & 31) << 2;
      *(float4*)&Ws[r * 128 + c4] = *(const float4*)(w1 + (size_t)(k0 + r) * 128 + c4);
    }
    __syncthreads();
#pragma unroll 4
    for (int k = 0; k < 64; ++k) {
      float4 wv = *(float4*)&Ws[k * 128 + c0];
      float xv[4];
#pragma unroll
      for (int i = 0; i < 4; ++i) xv[i] = Xs[r0 + i][k0 + k];
#pragma unroll
      for (int i = 0; i < 4; ++i) {
        a1[i][0] = fmaf(xv[i], wv.x, a1[i][0]);
        a1[i][1] = fmaf(xv[i], wv.y, a1[i][1]);
        a1[i][2] = fmaf(xv[i], wv.z, a1[i][2]);
        a1[i][3] = fmaf(xv[i], wv.w, a1[i][3]);
      }
    }
  }
#pragma unroll
  for (int i = 0; i < 4; ++i) {
    float4 o;
    o.x = fmaxf(a1[i][0] + b1[c0 + 0], 0.f);
    o.y = fmaxf(a1[i][1] + b1[c0 + 1], 0.f);
    o.z = fmaxf(a1[i][2] + b1[c0 + 2], 0.f);
    o.w = fmaxf(a1[i][3] + b1[c0 + 3], 0.f);
    *(float4*)&H1[r0 + i][c0] = o;
  }
  __syncthreads();
#pragma unroll
  for (int i = 0; i < 8; ++i) {
    int p = i * 256 + tid;
    int r = p >> 4, c4 = (p & 15) << 2;
    *(float4*)&Ws[r * 64 + c4] = *(const float4*)(w2 + (size_t)r * 64 + c4);
  }
  __syncthreads();
  int r2 = (tid >> 4) << 1;
  int c2 = (tid & 15) << 2;
  float a2[2][4] = {};
#pragma unroll 4
  for (int k = 0; k < 128; ++k) {
    float4 wv = *(float4*)&Ws[k * 64 + c2];
    float x0 = H1[r2][k], x1 = H1[r2 + 1][k];
    a2[0][0] = fmaf(x0, wv.x, a2[0][0]);
    a2[0][1] = fmaf(x0, wv.y, a2[0][1]);
    a2[0][2] = fmaf(x0, wv.z, a2[0][2]);
    a2[0][3] = fmaf(x0, wv.w, a2[0][3]);
    a2[1][0] = fmaf(x1, wv.x, a2[1][0]);
    a2[1][1] = fmaf(x1, wv.y, a2[1][1]);
    a2[1][2] = fmaf(x1, wv.z, a2[1][2]);
    a2[1][3] = fmaf(x1, wv.w, a2[1][3]);
  }
#pragma unroll
  for (int i = 0; i < 2; ++i) {
    float4 o;
    o.x = fmaxf(a2[i][0] + b2[c2 + 0], 0.f);
    o.y = fmaxf(a2[i][1] + b2[c2 + 1], 0.f);
    o.z = fmaxf(a2[i][2] + b2[c2 + 2], 0.f);
    o.w = fmaxf(a2[i][3] + b2[c2 + 3], 0.f);
    *(float4*)&H2[r2 + i][c2] = o;
  }
  __syncthreads();
  for (int p = tid; p < 352; p += 256) {
    int r = p / 11, c = p - (p / 11) * 11;
    float acc = b3[c];
#pragma unroll 8
    for (int k = 0; k < 64; ++k) acc = fmaf(H2[r][k], W3s[k][c], acc);
    if (m0 + r < NG) out[(size_t)(m0 + r) * 11 + c] = acc;
  }
}

extern "C" void kernel_launch(void* const* d_in, const int* in_sizes, int n_in,
                              void* d_out, int out_size, void* d_ws, size_t ws_size,
                              hipStream_t stream) {
  const float* x      = (const float*)d_in[0];
  const int*   ei     = (const int*)d_in[1];
  const int*   batch  = (const int*)d_in[2];
  const float* node_w = (const float*)d_in[3];
  const float* node_b = (const float*)d_in[4];
  const float* vn_w   = (const float*)d_in[5];
  const float* gin_w1 = (const float*)d_in[6];
  const float* gin_b1 = (const float*)d_in[7];
  const float* gin_w2 = (const float*)d_in[8];
  const float* gin_b2 = (const float*)d_in[9];
  const float* bn_g   = (const float*)d_in[10];
  const float* bn_b   = (const float*)d_in[11];
  const float* bn_m   = (const float*)d_in[12];
  const float* bn_v   = (const float*)d_in[13];
  const float* vn_w1  = (const float*)d_in[14];
  const float* vn_b1  = (const float*)d_in[15];
  const float* vbn1g  = (const float*)d_in[16];
  const float* vbn1b  = (const float*)d_in[17];
  const float* vbn1m  = (const float*)d_in[18];
  const float* vbn1v  = (const float*)d_in[19];
  const float* vn_w2  = (const float*)d_in[20];
  const float* vn_b2  = (const float*)d_in[21];
  const float* vbn2g  = (const float*)d_in[22];
  const float* vbn2b  = (const float*)d_in[23];
  const float* vbn2m  = (const float*)d_in[24];
  const float* vbn2v  = (const float*)d_in[25];
  const float* head_w1 = (const float*)d_in[26];
  const float* head_b1 = (const float*)d_in[27];
  const float* head_w2 = (const float*)d_in[28];
  const float* head_b2 = (const float*)d_in[29];
  const float* head_w3 = (const float*)d_in[30];
  const float* head_b3 = (const float*)d_in[31];

  // ---- workspace layout (~110 MB) ----
  unsigned short* h16   = (unsigned short*)d_ws;          // [NN*DD]
  unsigned short* u16   = h16 + (size_t)NN * DD;          // [NN*DD]
  unsigned short* vnb   = u16 + (size_t)NN * DD;          // [NG*DD]
  unsigned short* t0b   = vnb + (size_t)NG * DD;          // [NG*DD]
  unsigned short* wf1   = t0b + (size_t)NG * DD;          // [5*65536]
  unsigned short* wf2   = wf1 + 5 * 65536;                // [5*65536]
  unsigned short* wfv1  = wf2 + 5 * 65536;                // [4*65536]
  unsigned short* wfv2  = wfv1 + 4 * 65536;               // [4*65536]
  float* t0f  = (float*)(wfv2 + 4 * 65536);               // [NG*DD]
  int* rowptr = (int*)(t0f + (size_t)NG * DD);            // [NN+1]
  int* cursor = rowptr + NN + 1;                          // [NN]
  int* gstart = cursor + NN;                              // [NG]
  int* gend   = gstart + NG;                              // [NG]
  int* ssrc   = gend + NG;                                // [NE]
  int* bsum   = ssrc + NE;                                // [128]
  int* bbase  = bsum + 128;                               // [128]

  const int* src = ei;
  const int* dst = ei + NE;

  const int NB = (NN + 1023) / 1024;  // 98

  // ---- once per launch: weight pack + vn init + CSR + graph bounds ----
  k_pack_all<<<(18 * 65536 + NG * DD + 255) / 256, 256, 0, stream>>>(
      gin_w1, gin_w2, vn_w1, vn_w2, wf1, vn_w, vnb);
  k_zeroi<<<(NN + 2 * NG + 255) / 256, 256, 0, stream>>>(cursor, NN + 2 * NG);
  k_hist<<<(NE + 255) / 256, 256, 0, stream>>>(dst, cursor);
  k_bsum<<<NB, 1024, 0, stream>>>(cursor, bsum);
  k_scanb<<<1, 128, 0, stream>>>(bsum, bbase, NB);
  k_rowptr<<<NB, 1024, 0, stream>>>(cursor, bbase, rowptr, cursor);
  k_fill_src<<<(NE + 255) / 256, 256, 0, stream>>>(src, dst, cursor, ssrc);
  k_gbounds<<<(NN + 255) / 256, 256, 0, stream>>>(batch, gstart, gend);

  k_node_encode<<<NN / 16, 256, 0, stream>>>(x, node_w, node_b, h16);

  const int GG_NN = NN / 32;          // 3125
  const int GM_NG = (NG + 63) / 64;   // 32
  const int NU4   = NN * DD / 8;      // uint4 count

  for (int l = 0; l < NL; ++l) {
    // u = h + vn[batch]
    k_addvn_u<<<NU4 / 256, 256, 0, stream>>>(h16, vnb, batch, u16);
    // h = leaky(bn(relu((u[m]+sum u[src]) @ W1 + b1) @ W2 + b2))  [one kernel]
    k_gin_layer<<<GG_NN, 512, 0, stream>>>(
        u16, rowptr, ssrc,
        wf1 + (size_t)l * 65536, gin_b1 + l * DD,
        wf2 + (size_t)l * 65536, gin_b2 + l * DD,
        bn_g + l * DD, bn_b + l * DD, bn_m + l * DD, bn_v + l * DD, h16);
    if (l < NL - 1) {
      // t0 = pool(h) + vn  (bf16), then vn = vn_mlp(t0)  [one kernel]
      k_pool_seg<0><<<NG, 256, 0, stream>>>(h16, vnb, gstart, gend, t0b, nullptr);
      k_vn_mlp<<<GM_NG, 256, 0, stream>>>(
          t0b,
          wfv1 + (size_t)l * 65536, vn_b1 + l * DD,
          vbn1g + l * DD, vbn1b + l * DD, vbn1m + l * DD, vbn1v + l * DD,
          wfv2 + (size_t)l * 65536, vn_b2 + l * DD,
          vbn2g + l * DD, vbn2b + l * DD, vbn2m + l * DD, vbn2v + l * DD,
          vnb);
    }
  }
  // final pool (fp32, no vn) + fused head
  k_pool_seg<1><<<NG, 256, 0, stream>>>(h16, nullptr, gstart, gend, nullptr, t0f);
  k_head<<<(NG + 31) / 32, 256, 0, stream>>>(
      t0f, head_w1, head_b1, head_w2, head_b2, head_w3, head_b3, (float*)d_out);
}